// Round 1
// baseline (374.027 us; speedup 1.0000x reference)
//
#include <hip/hip_runtime.h>

typedef __bf16 bf16_t;
typedef __bf16 bf16x8 __attribute__((ext_vector_type(8)));
typedef __bf16 bf16x4 __attribute__((ext_vector_type(4)));
typedef float  f32x4  __attribute__((ext_vector_type(4)));

#define AS_G(p) ((const __attribute__((address_space(1))) void*)(p))
#define AS_L(p) ((__attribute__((address_space(3))) void*)(p))
#define GLD16(g, l) __builtin_amdgcn_global_load_lds(AS_G(g), AS_L(l), 16, 0, 0)

static __device__ __forceinline__ f32x4 mfma16(bf16x8 a, bf16x8 b, f32x4 c) {
  return __builtin_amdgcn_mfma_f32_16x16x32_bf16(a, b, c, 0, 0, 0);
}

// ---------------- fp32 -> bf16 convert (vectorized, grid-stride) ----------------
__global__ __launch_bounds__(256) void cvt_bf16_k(const float* __restrict__ in,
                                                  bf16_t* __restrict__ out, long n) {
  long i = ((long)blockIdx.x * 256 + threadIdx.x) * 4;
  long step = (long)gridDim.x * 256 * 4;
  for (; i < n; i += step) {
    float4 v = *(const float4*)(in + i);
    bf16x4 o;
    o[0] = (bf16_t)v.x; o[1] = (bf16_t)v.y; o[2] = (bf16_t)v.z; o[3] = (bf16_t)v.w;
    *(bf16x4*)(out + i) = o;
  }
}

// ---------------- W[K][N] f32 -> Wt[N][K] bf16 (tiled transpose) ----------------
__global__ __launch_bounds__(256) void tcvt_k(const float* __restrict__ W,
                                              bf16_t* __restrict__ Wt, int K, int N) {
  __shared__ float t[32][33];
  int k0 = blockIdx.y << 5, n0 = blockIdx.x << 5;
  int ti = threadIdx.x >> 3, tj = (threadIdx.x & 7) << 2;
  float4 v = *(const float4*)(W + (size_t)(k0 + ti) * N + n0 + tj);
  t[ti][tj] = v.x; t[ti][tj + 1] = v.y; t[ti][tj + 2] = v.z; t[ti][tj + 3] = v.w;
  __syncthreads();
  bf16x4 o;
  o[0] = (bf16_t)t[tj + 0][ti]; o[1] = (bf16_t)t[tj + 1][ti];
  o[2] = (bf16_t)t[tj + 2][ti]; o[3] = (bf16_t)t[tj + 3][ti];
  *(bf16x4*)(Wt + (size_t)(n0 + ti) * K + k0 + tj) = o;
}

// ---------------- V [BH][2048][64] -> Vt [BH][64][2048] ----------------
__global__ __launch_bounds__(256) void tv_k(const bf16_t* __restrict__ V,
                                            bf16_t* __restrict__ Vt) {
  __shared__ bf16_t t[64][72];
  int tid = threadIdx.x;
  int bh = blockIdx.y, s0 = blockIdx.x << 6;
  int si = tid >> 2, d0 = (tid & 3) << 4;
  const bf16_t* src = V + ((size_t)bh * 2048 + s0 + si) * 64 + d0;
  bf16x8 a = *(const bf16x8*)src;
  bf16x8 b = *(const bf16x8*)(src + 8);
#pragma unroll
  for (int j = 0; j < 8; j++) { t[si][d0 + j] = a[j]; t[si][d0 + 8 + j] = b[j]; }
  __syncthreads();
  int di = tid >> 2, s1 = (tid & 3) << 4;
  bf16x8 o1, o2;
#pragma unroll
  for (int j = 0; j < 8; j++) { o1[j] = t[s1 + j][di]; o2[j] = t[s1 + 8 + j][di]; }
  bf16_t* dst = Vt + ((size_t)bh * 64 + di) * 2048 + s0 + s1;
  *(bf16x8*)dst = o1;
  *(bf16x8*)(dst + 8) = o2;
}

// ---------------- GEMM: C[M][N] = A[M][K] @ Bt[N][K]^T ----------------
// 128x128 tile, BK=32, 4 waves, m97 structure + light XOR swizzle.
// MODE 0: write bf16, headed layout [B=row>>11, H=col>>6, s=row&2047, d=col&63], *oscale
// MODE 1: write f32 row-major + bias
template <int MODE>
__global__ __launch_bounds__(256) void gemm_bt_k(
    const bf16_t* __restrict__ A, const bf16_t* __restrict__ Bt,
    void* __restrict__ Cout, const float* __restrict__ bias,
    int N, int K, float oscale) {
  __shared__ __align__(16) char lA[8192];
  __shared__ __align__(16) char lB[8192];
  const int tid = threadIdx.x;
  const int lane = tid & 63;
  const int w = tid >> 6;
  const int wr = (w >> 1) << 6;
  const int wc = (w & 1) << 6;
  const long row0 = (long)blockIdx.y << 7;
  const long col0 = (long)blockIdx.x << 7;

  // staging: 64B rows; thread covers row tid>>2 (and +64), swizzled source
  const int r_st = tid >> 2;
  const int cb_st = ((tid & 3) << 4) ^ ((r_st & 3) << 4);
  const char* pa = (const char*)(A + (row0 + r_st) * (long)K) + cb_st;
  const char* pb = (const char*)(Bt + (col0 + r_st) * (long)K) + cb_st;
  const long step64 = (long)K * 128;  // 64 rows of K*2 bytes
  char* la = lA + tid * 16;
  char* lb = lB + tid * 16;

  f32x4 acc[4][4];
#pragma unroll
  for (int m = 0; m < 4; m++)
#pragma unroll
    for (int n = 0; n < 4; n++) acc[m][n] = f32x4{0.f, 0.f, 0.f, 0.f};

  for (int k0 = 0; k0 < K; k0 += 32) {
    __syncthreads();
    GLD16(pa, la); GLD16(pa + step64, la + 4096);
    GLD16(pb, lb); GLD16(pb + step64, lb + 4096);
    __syncthreads();
    pa += 64; pb += 64;
    bf16x8 af[4], bfr[4];
#pragma unroll
    for (int m = 0; m < 4; m++) {
      int row = wr + (m << 4) + (lane & 15);
      int cby = ((lane >> 4) << 4) ^ ((row & 3) << 4);
      af[m] = *(const bf16x8*)(lA + row * 64 + cby);
    }
#pragma unroll
    for (int n = 0; n < 4; n++) {
      int row = wc + (n << 4) + (lane & 15);
      int cby = ((lane >> 4) << 4) ^ ((row & 3) << 4);
      bfr[n] = *(const bf16x8*)(lB + row * 64 + cby);
    }
#pragma unroll
    for (int m = 0; m < 4; m++)
#pragma unroll
      for (int n = 0; n < 4; n++)
        acc[m][n] = mfma16(af[m], bfr[n], acc[m][n]);
  }

  if (MODE == 0) {
    bf16_t* Cb = (bf16_t*)Cout;
#pragma unroll
    for (int n = 0; n < 4; n++) {
      long c = col0 + wc + (n << 4) + (lane & 15);
      long h = c >> 6, d = c & 63;
#pragma unroll
      for (int m = 0; m < 4; m++) {
#pragma unroll
        for (int j = 0; j < 4; j++) {
          long rr = row0 + wr + (m << 4) + ((lane >> 4) << 2) + j;
          long bb = rr >> 11, s = rr & 2047;
          Cb[(((bb << 4) + h) * 2048 + s) * 64 + d] = (bf16_t)(acc[m][n][j] * oscale);
        }
      }
    }
  } else {
    float* Cf = (float*)Cout;
#pragma unroll
    for (int n = 0; n < 4; n++) {
      long c = col0 + wc + (n << 4) + (lane & 15);
      float bv = bias[c];
#pragma unroll
      for (int m = 0; m < 4; m++) {
#pragma unroll
        for (int j = 0; j < 4; j++) {
          long rr = row0 + wr + (m << 4) + ((lane >> 4) << 2) + j;
          Cf[rr * (long)N + c] = acc[m][n][j] + bv;
        }
      }
    }
  }
}

// ---------------- Flash attention ----------------
// Q [BH][2048][64] bf16 (pre-scaled by SCALE*log2e), K [BH][2048][64], VT [BH][64][2048]
// O [B][2048][H*64] bf16.  4 waves x 16 q-rows, KVBLK=64.
__global__ __launch_bounds__(256) void attn_k(
    const bf16_t* __restrict__ Q, const bf16_t* __restrict__ Kh,
    const bf16_t* __restrict__ VT, bf16_t* __restrict__ O) {
  __shared__ __align__(16) char lK[8192];
  __shared__ __align__(16) char lV[8192];
  __shared__ __align__(16) char lP[4][2048];
  const int tid = threadIdx.x;
  const int lane = tid & 63;
  const int w = tid >> 6;
  const int bh = blockIdx.y;
  const int q0 = blockIdx.x << 6;
  const int b = bh >> 4, h = bh & 15;

  // Q fragments stay in registers (A-operand layout: row=lane&15, k=8*(lane>>4)+j)
  const bf16_t* qbase =
      Q + ((size_t)bh * 2048 + q0 + w * 16 + (lane & 15)) * 64 + ((lane >> 4) << 3);
  bf16x8 qf0 = *(const bf16x8*)qbase;
  bf16x8 qf1 = *(const bf16x8*)(qbase + 32);

  float m_[4], l_[4];
  f32x4 o_[4];
#pragma unroll
  for (int j = 0; j < 4; j++) { m_[j] = -3.0e38f; l_[j] = 0.f; }
#pragma unroll
  for (int dt = 0; dt < 4; dt++) o_[dt] = f32x4{0.f, 0.f, 0.f, 0.f};

  // staging coords: 8KB tiles of 128B rows; swizzled global source
  const int r_st = tid >> 3;  // 0..31 (+32 on second pass)
  const int cb_st = ((tid & 7) << 4) ^ ((r_st & 7) << 4);
  const char* pk = (const char*)(Kh + (size_t)bh * 2048 * 64) + r_st * 128 + cb_st;
  const char* pv = (const char*)(VT + (size_t)bh * 64 * 2048) + r_st * 4096 + cb_st;
  char* lkd = lK + tid * 16;
  char* lvd = lV + tid * 16;
  char* lPw = lP[w];

  for (int it = 0; it < 32; it++) {
    __syncthreads();
    GLD16(pk, lkd); GLD16(pk + 4096, lkd + 4096);
    GLD16(pv, lvd); GLD16(pv + 131072, lvd + 4096);
    __syncthreads();
    pk += 8192; pv += 128;

    // S = Q @ K^T  (B-operand: col=lane&15 -> K row; k=8*(lane>>4)+j)
    f32x4 s[4];
#pragma unroll
    for (int ct = 0; ct < 4; ct++) {
      int n = (ct << 4) + (lane & 15);
      int sw = (n & 7) << 4;
      bf16x8 k0f = *(const bf16x8*)(lK + n * 128 + (((lane >> 4) << 4) ^ sw));
      bf16x8 k1f = *(const bf16x8*)(lK + n * 128 + ((64 + ((lane >> 4) << 4)) ^ sw));
      f32x4 t = f32x4{0.f, 0.f, 0.f, 0.f};
      t = mfma16(qf0, k0f, t);
      t = mfma16(qf1, k1f, t);
      s[ct] = t;
    }

    // online softmax (rows live in 16-lane groups; reduce across cols)
    float mx[4], rs[4], al[4];
#pragma unroll
    for (int j = 0; j < 4; j++)
      mx[j] = fmaxf(fmaxf(s[0][j], s[1][j]), fmaxf(s[2][j], s[3][j]));
#pragma unroll
    for (int dd = 1; dd < 16; dd <<= 1)
#pragma unroll
      for (int j = 0; j < 4; j++) mx[j] = fmaxf(mx[j], __shfl_xor(mx[j], dd));
#pragma unroll
    for (int j = 0; j < 4; j++) {
      float mn = fmaxf(m_[j], mx[j]);
      al[j] = exp2f(m_[j] - mn);
      m_[j] = mn;
      rs[j] = 0.f;
    }
#pragma unroll
    for (int ct = 0; ct < 4; ct++)
#pragma unroll
      for (int j = 0; j < 4; j++) {
        float p = exp2f(s[ct][j] - m_[j]);
        s[ct][j] = p;
        rs[j] += p;
      }
#pragma unroll
    for (int dd = 1; dd < 16; dd <<= 1)
#pragma unroll
      for (int j = 0; j < 4; j++) rs[j] += __shfl_xor(rs[j], dd);
#pragma unroll
    for (int j = 0; j < 4; j++) l_[j] = l_[j] * al[j] + rs[j];
#pragma unroll
    for (int dt = 0; dt < 4; dt++)
#pragma unroll
      for (int j = 0; j < 4; j++) o_[dt][j] *= al[j];

    // P -> per-wave LDS (bf16, swizzled), then PV
#pragma unroll
    for (int ct = 0; ct < 4; ct++)
#pragma unroll
      for (int j = 0; j < 4; j++) {
        int qr = ((lane >> 4) << 2) + j;
        int c = (ct << 4) + (lane & 15);
        *(bf16_t*)(lPw + qr * 128 + ((c * 2) ^ ((qr & 7) << 4))) = (bf16_t)s[ct][j];
      }
#pragma unroll
    for (int kk = 0; kk < 2; kk++) {
      int qr = lane & 15;
      bf16x8 pf = *(const bf16x8*)(lPw + qr * 128 +
                                   (((kk << 6) + ((lane >> 4) << 4)) ^ ((qr & 7) << 4)));
#pragma unroll
      for (int dt = 0; dt < 4; dt++) {
        int dr = (dt << 4) + (lane & 15);
        bf16x8 vf = *(const bf16x8*)(lV + dr * 128 +
                                     (((kk << 6) + ((lane >> 4) << 4)) ^ ((dr & 7) << 4)));
        o_[dt] = mfma16(pf, vf, o_[dt]);
      }
    }
  }

#pragma unroll
  for (int j = 0; j < 4; j++) l_[j] = 1.0f / l_[j];
  bf16_t* Ob = O + (size_t)b * 2048 * 1024 + (size_t)h * 64;
#pragma unroll
  for (int dt = 0; dt < 4; dt++)
#pragma unroll
    for (int j = 0; j < 4; j++) {
      int s_ = q0 + w * 16 + ((lane >> 4) << 2) + j;
      int d = (dt << 4) + (lane & 15);
      Ob[(size_t)s_ * 1024 + d] = (bf16_t)(o_[dt][j] * l_[j]);
    }
}

extern "C" void kernel_launch(void* const* d_in, const int* in_sizes, int n_in,
                              void* d_out, int out_size, void* d_ws, size_t ws_size,
                              hipStream_t stream) {
  (void)in_sizes; (void)n_in; (void)out_size; (void)ws_size;
  const float* x   = (const float*)d_in[0];
  const float* ctx = (const float*)d_in[1];
  const float* w_q = (const float*)d_in[2];
  const float* w_k = (const float*)d_in[3];
  const float* w_v = (const float*)d_in[4];
  const float* w_o = (const float*)d_in[5];
  const float* b_o = (const float*)d_in[6];

  char* ws = (char*)d_ws;
  const size_t MB = 1 << 20;
  bf16_t* xb  = (bf16_t*)(ws);                       // 16 MB (reused as O after x dead)
  bf16_t* cb  = (bf16_t*)(ws + 16 * MB);             // 12 MB
  bf16_t* wqT = (bf16_t*)(ws + 28 * MB);             // 2 MB
  bf16_t* wkT = (bf16_t*)(ws + 30 * MB);             // 1.5 MB
  bf16_t* wvT = (bf16_t*)(ws + 31 * MB + 512 * 1024);// 1.5 MB
  bf16_t* woT = (bf16_t*)(ws + 33 * MB);             // 2 MB
  bf16_t* qws = (bf16_t*)(ws + 35 * MB);             // 16 MB
  bf16_t* kws = (bf16_t*)(ws + 51 * MB);             // 16 MB
  bf16_t* vws = (bf16_t*)(ws + 67 * MB);             // 16 MB
  bf16_t* vtw = (bf16_t*)(ws + 83 * MB);             // 16 MB (total 99 MB)
  bf16_t* ows = xb;                                  // alias: x is dead after Q proj

  cvt_bf16_k<<<2048, 256, 0, stream>>>(x, xb, 8388608L);
  cvt_bf16_k<<<2048, 256, 0, stream>>>(ctx, cb, 6291456L);
  tcvt_k<<<dim3(32, 32), 256, 0, stream>>>(w_q, wqT, 1024, 1024);
  tcvt_k<<<dim3(32, 24), 256, 0, stream>>>(w_k, wkT, 768, 1024);
  tcvt_k<<<dim3(32, 24), 256, 0, stream>>>(w_v, wvT, 768, 1024);
  tcvt_k<<<dim3(32, 32), 256, 0, stream>>>(w_o, woT, 1024, 1024);

  const float qs = 0.125f * 1.4426950408889634f;  // SCALE * log2(e)
  gemm_bt_k<0><<<dim3(8, 64), 256, 0, stream>>>(xb, wqT, qws, nullptr, 1024, 1024, qs);
  gemm_bt_k<0><<<dim3(8, 64), 256, 0, stream>>>(cb, wkT, kws, nullptr, 1024, 768, 1.0f);
  gemm_bt_k<0><<<dim3(8, 64), 256, 0, stream>>>(cb, wvT, vws, nullptr, 1024, 768, 1.0f);
  tv_k<<<dim3(32, 64), 256, 0, stream>>>(vws, vtw);
  attn_k<<<dim3(32, 64), 256, 0, stream>>>(qws, kws, vtw, ows);
  gemm_bt_k<1><<<dim3(8, 64), 256, 0, stream>>>(ows, woT, d_out, b_o, 1024, 1024, 1.0f);
}